// Round 1
// baseline (3928.156 us; speedup 1.0000x reference)
//
#include <hip/hip_runtime.h>

#define TT 300
#define FF 39
#define H1C 35
#define H2C 30
#define IN1 74          // FF + H1C
#define IN2 65          // H1C + H2C
#define BB 4096
#define RPB 16          // batch rows per block
#define TX 40           // k-lanes (k < 35 / k < 30 active)
#define TY 8            // row-pairs (rows ty and ty+8)
#define NTH (TX*TY)     // 320 threads = 5 waves
#define NFC1 50
#define NFC2 40
#define RNNCH 60

__device__ __forceinline__ float sigf(float v) { return 1.0f/(1.0f + __expf(-v)); }
__device__ __forceinline__ float tanh_(float v) { return 1.0f - 2.0f/(__expf(2.0f*v) + 1.0f); }

// Persistent bidirectional stacked-LSTM kernel. blockIdx.y = direction.
__global__ __launch_bounds__(NTH)
void lstm2_kernel(const float* __restrict__ x,
                  const float* __restrict__ Wf1, const float* __restrict__ Bf1,
                  const float* __restrict__ Wf2, const float* __restrict__ Bf2,
                  const float* __restrict__ Wb1, const float* __restrict__ Bb1,
                  const float* __restrict__ Wb2, const float* __restrict__ Bb2,
                  float* __restrict__ rnn)
{
    // weights: [k][c] -> float4 of 4 gate columns (i,j,f,o)
    __shared__ __align__(16) float4 w1v[H1C*IN1];   // 41440 B
    __shared__ __align__(16) float4 w2v[H2C*IN2];   // 31200 B
    __shared__ __align__(16) float in1[RPB][IN1];   // x(39) || h1(35)   4736 B
    __shared__ __align__(16) float in2[RPB][IN2+1]; // h1(35) || h2(30)  4224 B
    // total LDS = 81600 B  (<= 81920 -> 2 blocks/CU)

    const int dir = blockIdx.y;
    const int b0  = blockIdx.x * RPB;
    const float* W1 = dir ? Wb1 : Wf1;
    const float* B1 = dir ? Bb1 : Bf1;
    const float* W2 = dir ? Wb2 : Wf2;
    const float* B2 = dir ? Bb2 : Bf2;

    const int tx = threadIdx.x, ty = threadIdx.y;
    const int tid = ty*TX + tx;

    // stage weights: w1v[k*IN1+c].g = W1[c][g*35+k]
    for (int i = tid; i < H1C*IN1*4; i += NTH) {
        int kc = i >> 2, g = i & 3;
        int k = kc / IN1, c = kc % IN1;
        ((float*)w1v)[i] = W1[c*(4*H1C) + g*H1C + k];
    }
    for (int i = tid; i < H2C*IN2*4; i += NTH) {
        int kc = i >> 2, g = i & 3;
        int k = kc / IN2, c = kc % IN2;
        ((float*)w2v)[i] = W2[c*(4*H2C) + g*H2C + k];
    }
    for (int i = tid; i < RPB*IN1; i += NTH) ((float*)in1)[i] = 0.0f;
    for (int i = tid; i < RPB*(IN2+1); i += NTH) ((float*)in2)[i] = 0.0f;
    __syncthreads();

    // load x(t=first) into in1 x-part
    const int t0in = dir ? (TT-1) : 0;
    for (int i = tid; i < RPB*FF; i += NTH) {
        int r = i / FF, f = i % FF;
        in1[r][f] = x[((size_t)(b0+r)*TT + t0in)*FF + f];
    }

    float bias1[4], bias2[4];
    if (tx < H1C) {
        #pragma unroll
        for (int g = 0; g < 4; ++g) bias1[g] = B1[g*H1C + tx];
    }
    if (tx < H2C) {
        #pragma unroll
        for (int g = 0; g < 4; ++g) bias2[g] = B2[g*H2C + tx];
    }

    // x-prefetch mapping (invariant over t)
    const int p0r = tid / FF, p0f = tid % FF;
    const int i1i = tid + NTH;
    const bool p1v = (i1i < RPB*FF);
    const int p1r = p1v ? (i1i / FF) : 0, p1f = p1v ? (i1i % FF) : 0;
    const size_t xb0 = (size_t)(b0+p0r)*TT*FF + p0f;
    const size_t xb1 = (size_t)(b0+p1r)*TT*FF + p1f;

    const int r0 = ty, r1 = ty + TY;
    float c1a = 0.f, c1b = 0.f, c2a = 0.f, c2b = 0.f;

    const size_t rb0 = ((size_t)(b0+r0)*TT)*RNNCH + dir*H2C + tx;
    const size_t rb1 = ((size_t)(b0+r1)*TT)*RNNCH + dir*H2C + tx;

    __syncthreads();

    #pragma unroll 1
    for (int t = 0; t < TT; ++t) {
        // prefetch x(t+1) into registers (hidden under GEMM1)
        float px0 = 0.f, px1 = 0.f;
        if (t < TT-1) {
            const int tn = dir ? (TT-2-t) : (t+1);
            px0 = x[xb0 + (size_t)tn*FF];
            if (p1v) px1 = x[xb1 + (size_t)tn*FF];
        }

        // ---- layer-1 GEMM: z1 = [x_t | h1] @ W1 ----
        float a00=0,a01=0,a02=0,a03=0,a10=0,a11=0,a12=0,a13=0;
        if (tx < H1C) {
            const float4* __restrict__ wp = w1v + tx*IN1;
            const float* __restrict__ u = in1[r0];
            const float* __restrict__ v = in1[r1];
            #pragma unroll
            for (int c = 0; c < IN1; c += 2) {
                float4 w0 = wp[c];
                float4 w1 = wp[c+1];
                float2 ua = *(const float2*)(u + c);
                float2 va = *(const float2*)(v + c);
                a00 += ua.x*w0.x; a01 += ua.x*w0.y; a02 += ua.x*w0.z; a03 += ua.x*w0.w;
                a10 += va.x*w0.x; a11 += va.x*w0.y; a12 += va.x*w0.z; a13 += va.x*w0.w;
                a00 += ua.y*w1.x; a01 += ua.y*w1.y; a02 += ua.y*w1.z; a03 += ua.y*w1.w;
                a10 += va.y*w1.x; a11 += va.y*w1.y; a12 += va.y*w1.z; a13 += va.y*w1.w;
            }
        }
        __syncthreads();   // A: all in1 reads done

        if (tx < H1C) {
            float i0 = a00+bias1[0], j0 = a01+bias1[1], f0 = a02+bias1[2], o0 = a03+bias1[3];
            c1a = sigf(f0+1.0f)*c1a + sigf(i0)*tanh_(j0);
            float h0 = sigf(o0)*tanh_(c1a);
            float i1 = a10+bias1[0], j1 = a11+bias1[1], f1 = a12+bias1[2], o1 = a13+bias1[3];
            c1b = sigf(f1+1.0f)*c1b + sigf(i1)*tanh_(j1);
            float h1 = sigf(o1)*tanh_(c1b);
            in1[r0][FF+tx] = h0; in2[r0][tx] = h0;
            in1[r1][FF+tx] = h1; in2[r1][tx] = h1;
        }
        if (t < TT-1) {
            in1[p0r][p0f] = px0;
            if (p1v) in1[p1r][p1f] = px1;
        }
        __syncthreads();   // B: in1/in2 updated for this step

        // ---- layer-2 GEMM: z2 = [h1 | h2] @ W2 ----
        float g00=0,g01=0,g02=0,g03=0,g10=0,g11=0,g12=0,g13=0;
        if (tx < H2C) {
            const float4* __restrict__ wp = w2v + tx*IN2;
            const float* __restrict__ u = in2[r0];
            const float* __restrict__ v = in2[r1];
            #pragma unroll
            for (int c = 0; c < IN2-1; c += 2) {
                float4 w0 = wp[c];
                float4 w1 = wp[c+1];
                float2 ua = *(const float2*)(u + c);
                float2 va = *(const float2*)(v + c);
                g00 += ua.x*w0.x; g01 += ua.x*w0.y; g02 += ua.x*w0.z; g03 += ua.x*w0.w;
                g10 += va.x*w0.x; g11 += va.x*w0.y; g12 += va.x*w0.z; g13 += va.x*w0.w;
                g00 += ua.y*w1.x; g01 += ua.y*w1.y; g02 += ua.y*w1.z; g03 += ua.y*w1.w;
                g10 += va.y*w1.x; g11 += va.y*w1.y; g12 += va.y*w1.z; g13 += va.y*w1.w;
            }
            {   // tail c = 64
                float4 w0 = wp[IN2-1];
                float ue = u[IN2-1], ve = v[IN2-1];
                g00 += ue*w0.x; g01 += ue*w0.y; g02 += ue*w0.z; g03 += ue*w0.w;
                g10 += ve*w0.x; g11 += ve*w0.y; g12 += ve*w0.z; g13 += ve*w0.w;
            }
        }
        __syncthreads();   // C: all in2 reads done

        if (tx < H2C) {
            float i0 = g00+bias2[0], j0 = g01+bias2[1], f0 = g02+bias2[2], o0 = g03+bias2[3];
            c2a = sigf(f0+1.0f)*c2a + sigf(i0)*tanh_(j0);
            float h0 = sigf(o0)*tanh_(c2a);
            float i1 = g10+bias2[0], j1 = g11+bias2[1], f1 = g12+bias2[2], o1 = g13+bias2[3];
            c2b = sigf(f1+1.0f)*c2b + sigf(i1)*tanh_(j1);
            float h1 = sigf(o1)*tanh_(c2b);
            in2[r0][H1C+tx] = h0;
            in2[r1][H1C+tx] = h1;
            const int tout = dir ? (TT-1-t) : t;
            rnn[rb0 + (size_t)tout*RNNCH] = h0;
            rnn[rb1 + (size_t)tout*RNNCH] = h1;
        }
        // writes above are separated from next-step reads by barriers A/B of t+1
    }
}

// Pointwise 3-layer MLP on the concatenated rnn features.
__global__ __launch_bounds__(256)
void fc_kernel(const float* __restrict__ rnn,
               const float* __restrict__ W1, const float* __restrict__ B1,
               const float* __restrict__ W2, const float* __restrict__ B2,
               const float* __restrict__ W3, const float* __restrict__ B3,
               float* __restrict__ out)
{
    __shared__ float w1s[RNNCH][52];     // padded stride for alignment
    __shared__ float w2s[NFC1*NFC2];
    __shared__ float w3s[NFC2*2];
    __shared__ float b1s[NFC1], b2s[NFC2], b3s[2];
    const int tid = threadIdx.x;
    for (int i = tid; i < RNNCH*NFC1; i += 256) w1s[i/NFC1][i%NFC1] = W1[i];
    for (int i = tid; i < NFC1*NFC2; i += 256) w2s[i] = W2[i];
    for (int i = tid; i < NFC2*2;   i += 256) w3s[i] = W3[i];
    if (tid < NFC1) b1s[tid] = B1[tid];
    if (tid < NFC2) b2s[tid] = B2[tid];
    if (tid < 2)    b3s[tid] = B3[tid];
    __syncthreads();

    const size_t row = (size_t)blockIdx.x*256 + tid;
    const float* __restrict__ in = rnn + row*RNNCH;

    float h[NFC1];
    #pragma unroll
    for (int j = 0; j < NFC1; ++j) h[j] = b1s[j];
    #pragma unroll 4
    for (int c = 0; c < RNNCH; ++c) {
        float v = in[c];
        #pragma unroll
        for (int j = 0; j < NFC1; ++j) h[j] += v * w1s[c][j];
    }
    #pragma unroll
    for (int j = 0; j < NFC1; ++j) h[j] = fmaxf(h[j], 0.0f);

    float h2[NFC2];
    #pragma unroll
    for (int j = 0; j < NFC2; ++j) h2[j] = b2s[j];
    #pragma unroll        // full unroll: h[c] must be a static register index
    for (int c = 0; c < NFC1; ++c) {
        float v = h[c];
        #pragma unroll
        for (int j = 0; j < NFC2; ++j) h2[j] += v * w2s[c*NFC2 + j];
    }
    #pragma unroll
    for (int j = 0; j < NFC2; ++j) h2[j] = fmaxf(h2[j], 0.0f);

    float o0 = b3s[0], o1 = b3s[1];
    #pragma unroll        // full unroll: h2[c] static index
    for (int c = 0; c < NFC2; ++c) {
        o0 += h2[c] * w3s[c*2];
        o1 += h2[c] * w3s[c*2+1];
    }
    ((float2*)out)[row] = make_float2(o0, o1);
}

extern "C" void kernel_launch(void* const* d_in, const int* in_sizes, int n_in,
                              void* d_out, int out_size, void* d_ws, size_t ws_size,
                              hipStream_t stream) {
    (void)in_sizes; (void)n_in; (void)out_size; (void)ws_size;
    const float* x     = (const float*)d_in[0];
    const float* w_fw1 = (const float*)d_in[1];
    const float* b_fw1 = (const float*)d_in[2];
    const float* w_fw2 = (const float*)d_in[3];
    const float* b_fw2 = (const float*)d_in[4];
    const float* w_bw1 = (const float*)d_in[5];
    const float* b_bw1 = (const float*)d_in[6];
    const float* w_bw2 = (const float*)d_in[7];
    const float* b_bw2 = (const float*)d_in[8];
    const float* w_fc1 = (const float*)d_in[9];
    const float* b_fc1 = (const float*)d_in[10];
    const float* w_fc2 = (const float*)d_in[11];
    const float* b_fc2 = (const float*)d_in[12];
    const float* w_fc3 = (const float*)d_in[13];
    const float* b_fc3 = (const float*)d_in[14];
    float* out = (float*)d_out;

    float* rnn = (float*)d_ws;                 // B*T*60 floats = ~295 MB

    dim3 gl(BB/RPB, 2), bl(TX, TY);
    lstm2_kernel<<<gl, bl, 0, stream>>>(x, w_fw1, b_fw1, w_fw2, b_fw2,
                                        w_bw1, b_bw1, w_bw2, b_bw2, rnn);

    const int total = BB * TT;                  // 1,228,800 (exact multiple of 256)
    fc_kernel<<<total/256, 256, 0, stream>>>(rnn, w_fc1, b_fc1, w_fc2, b_fc2,
                                             w_fc3, b_fc3, out);
}

// Round 2
// 3016.260 us; speedup vs baseline: 1.3023x; 1.3023x over previous
//
#include <hip/hip_runtime.h>

#define TT 300
#define FF 39
#define H1C 35
#define H2C 30
#define IN1 74          // FF + H1C
#define IN2 65          // H1C + H2C
#define BB 4096
#define RPB 32          // batch rows per block
#define TX 40           // k-lanes (k < 35 / k < 30 active)
#define TY 16           // row-pairs (rows ty and ty+16)
#define NTH (TX*TY)     // 640 threads = 10 waves
#define NFC1 50
#define NFC2 40
#define RNNCH 60

__device__ __forceinline__ float sigf(float v) { return 1.0f/(1.0f + __expf(-v)); }
__device__ __forceinline__ float tanh_(float v) { return 1.0f - 2.0f/(__expf(2.0f*v) + 1.0f); }

// Persistent bidirectional stacked-LSTM kernel. blockIdx.y = direction.
// 256 blocks total = 1 block/CU, 10 waves/CU.
__global__ __launch_bounds__(NTH)
void lstm2_kernel(const float* __restrict__ x,
                  const float* __restrict__ Wf1, const float* __restrict__ Bf1,
                  const float* __restrict__ Wf2, const float* __restrict__ Bf2,
                  const float* __restrict__ Wb1, const float* __restrict__ Bb1,
                  const float* __restrict__ Wb2, const float* __restrict__ Bb2,
                  float* __restrict__ rnn)
{
    // weights laid out [c][k] -> lanes (tx) read CONTIGUOUS float4s: conflict-free
    __shared__ __align__(16) float4 w1v[IN1*H1C];   // 41440 B : w1v[c*35+k] = gates(i,j,f,o) of col k
    __shared__ __align__(16) float4 w2v[IN2*H2C];   // 31200 B
    __shared__ __align__(16) float in1[RPB][IN1];   // x(39) || h1(35)   9472 B
    __shared__ __align__(16) float in2[RPB][IN2+1]; // h1(35) || h2(30)  8448 B
    // total LDS = 90560 B -> 1 block/CU (intentional)

    const int dir = blockIdx.y;
    const int b0  = blockIdx.x * RPB;
    const float* W1 = dir ? Wb1 : Wf1;
    const float* B1 = dir ? Bb1 : Bf1;
    const float* W2 = dir ? Wb2 : Wf2;
    const float* B2 = dir ? Bb2 : Bf2;

    const int tx = threadIdx.x, ty = threadIdx.y;
    const int tid = ty*TX + tx;

    // stage weights: w1v[c*H1C+k].g = W1[c][g*H1C+k]
    for (int i = tid; i < IN1*H1C*4; i += NTH) {
        int q = i >> 2, g = i & 3;
        int c = q / H1C, k = q % H1C;
        ((float*)w1v)[i] = W1[c*(4*H1C) + g*H1C + k];
    }
    for (int i = tid; i < IN2*H2C*4; i += NTH) {
        int q = i >> 2, g = i & 3;
        int c = q / H2C, k = q % H2C;
        ((float*)w2v)[i] = W2[c*(4*H2C) + g*H2C + k];
    }
    for (int i = tid; i < RPB*IN1; i += NTH) ((float*)in1)[i] = 0.0f;
    for (int i = tid; i < RPB*(IN2+1); i += NTH) ((float*)in2)[i] = 0.0f;
    __syncthreads();

    // load x(t=first) into in1 x-part
    const int t0in = dir ? (TT-1) : 0;
    for (int i = tid; i < RPB*FF; i += NTH) {
        int r = i / FF, f = i % FF;
        in1[r][f] = x[((size_t)(b0+r)*TT + t0in)*FF + f];
    }

    float bias1[4], bias2[4];
    if (tx < H1C) {
        #pragma unroll
        for (int g = 0; g < 4; ++g) bias1[g] = B1[g*H1C + tx];
    }
    if (tx < H2C) {
        #pragma unroll
        for (int g = 0; g < 4; ++g) bias2[g] = B2[g*H2C + tx];
    }

    // x-prefetch mapping (invariant over t): RPB*FF = 1248 elements, 640 threads
    const int p0r = tid / FF, p0f = tid % FF;
    const int i1i = tid + NTH;
    const bool p1v = (i1i < RPB*FF);
    const int p1r = p1v ? (i1i / FF) : 0, p1f = p1v ? (i1i % FF) : 0;
    const size_t xb0 = (size_t)(b0+p0r)*TT*FF + p0f;
    const size_t xb1 = (size_t)(b0+p1r)*TT*FF + p1f;

    const int r0 = ty, r1 = ty + TY;
    float c1a = 0.f, c1b = 0.f, c2a = 0.f, c2b = 0.f;

    const size_t rb0 = ((size_t)(b0+r0)*TT)*RNNCH + dir*H2C + tx;
    const size_t rb1 = ((size_t)(b0+r1)*TT)*RNNCH + dir*H2C + tx;

    __syncthreads();

    #pragma unroll 1
    for (int t = 0; t < TT; ++t) {
        // prefetch x(t+1) into registers (hidden under GEMM1)
        float px0 = 0.f, px1 = 0.f;
        if (t < TT-1) {
            const int tn = dir ? (TT-2-t) : (t+1);
            px0 = x[xb0 + (size_t)tn*FF];
            if (p1v) px1 = x[xb1 + (size_t)tn*FF];
        }

        // ---- layer-1 GEMM: z1 = [x_t | h1] @ W1 ----
        float a00=0,a01=0,a02=0,a03=0,a10=0,a11=0,a12=0,a13=0;
        if (tx < H1C) {
            const float4* __restrict__ wp = w1v + tx;
            const float* __restrict__ u = in1[r0];
            const float* __restrict__ v = in1[r1];
            #pragma unroll
            for (int c = 0; c < IN1; c += 2) {
                float4 w0 = wp[c*H1C];
                float4 w1 = wp[(c+1)*H1C];
                float2 ua = *(const float2*)(u + c);
                float2 va = *(const float2*)(v + c);
                a00 += ua.x*w0.x; a01 += ua.x*w0.y; a02 += ua.x*w0.z; a03 += ua.x*w0.w;
                a10 += va.x*w0.x; a11 += va.x*w0.y; a12 += va.x*w0.z; a13 += va.x*w0.w;
                a00 += ua.y*w1.x; a01 += ua.y*w1.y; a02 += ua.y*w1.z; a03 += ua.y*w1.w;
                a10 += va.y*w1.x; a11 += va.y*w1.y; a12 += va.y*w1.z; a13 += va.y*w1.w;
            }
        }
        __syncthreads();   // A: all in1 reads done

        if (tx < H1C) {
            float i0 = a00+bias1[0], j0 = a01+bias1[1], f0 = a02+bias1[2], o0 = a03+bias1[3];
            c1a = sigf(f0+1.0f)*c1a + sigf(i0)*tanh_(j0);
            float h0 = sigf(o0)*tanh_(c1a);
            float i1 = a10+bias1[0], j1 = a11+bias1[1], f1 = a12+bias1[2], o1 = a13+bias1[3];
            c1b = sigf(f1+1.0f)*c1b + sigf(i1)*tanh_(j1);
            float h1 = sigf(o1)*tanh_(c1b);
            in1[r0][FF+tx] = h0; in2[r0][tx] = h0;
            in1[r1][FF+tx] = h1; in2[r1][tx] = h1;
        }
        if (t < TT-1) {
            in1[p0r][p0f] = px0;
            if (p1v) in1[p1r][p1f] = px1;
        }
        __syncthreads();   // B: in1/in2 updated for this step

        // ---- layer-2 GEMM: z2 = [h1 | h2] @ W2 ----
        float g00=0,g01=0,g02=0,g03=0,g10=0,g11=0,g12=0,g13=0;
        if (tx < H2C) {
            const float4* __restrict__ wp = w2v + tx;
            const float* __restrict__ u = in2[r0];
            const float* __restrict__ v = in2[r1];
            #pragma unroll
            for (int c = 0; c < IN2-1; c += 2) {
                float4 w0 = wp[c*H2C];
                float4 w1 = wp[(c+1)*H2C];
                float2 ua = *(const float2*)(u + c);
                float2 va = *(const float2*)(v + c);
                g00 += ua.x*w0.x; g01 += ua.x*w0.y; g02 += ua.x*w0.z; g03 += ua.x*w0.w;
                g10 += va.x*w0.x; g11 += va.x*w0.y; g12 += va.x*w0.z; g13 += va.x*w0.w;
                g00 += ua.y*w1.x; g01 += ua.y*w1.y; g02 += ua.y*w1.z; g03 += ua.y*w1.w;
                g10 += va.y*w1.x; g11 += va.y*w1.y; g12 += va.y*w1.z; g13 += va.y*w1.w;
            }
            {   // tail c = 64
                float4 w0 = wp[(IN2-1)*H2C];
                float ue = u[IN2-1], ve = v[IN2-1];
                g00 += ue*w0.x; g01 += ue*w0.y; g02 += ue*w0.z; g03 += ue*w0.w;
                g10 += ve*w0.x; g11 += ve*w0.y; g12 += ve*w0.z; g13 += ve*w0.w;
            }
        }
        __syncthreads();   // C: all in2 reads done

        if (tx < H2C) {
            float i0 = g00+bias2[0], j0 = g01+bias2[1], f0 = g02+bias2[2], o0 = g03+bias2[3];
            c2a = sigf(f0+1.0f)*c2a + sigf(i0)*tanh_(j0);
            float h0 = sigf(o0)*tanh_(c2a);
            float i1 = g10+bias2[0], j1 = g11+bias2[1], f1 = g12+bias2[2], o1 = g13+bias2[3];
            c2b = sigf(f1+1.0f)*c2b + sigf(i1)*tanh_(j1);
            float h1 = sigf(o1)*tanh_(c2b);
            in2[r0][H1C+tx] = h0;
            in2[r1][H1C+tx] = h1;
            const int tout = dir ? (TT-1-t) : t;
            rnn[rb0 + (size_t)tout*RNNCH] = h0;
            rnn[rb1 + (size_t)tout*RNNCH] = h1;
        }
        // writes above are separated from next-step reads by barriers A/B of t+1
    }
}

// Pointwise 3-layer MLP on the concatenated rnn features.
__global__ __launch_bounds__(256)
void fc_kernel(const float* __restrict__ rnn,
               const float* __restrict__ W1, const float* __restrict__ B1,
               const float* __restrict__ W2, const float* __restrict__ B2,
               const float* __restrict__ W3, const float* __restrict__ B3,
               float* __restrict__ out)
{
    __shared__ float w1s[RNNCH][52];     // padded stride for alignment
    __shared__ float w2s[NFC1*NFC2];
    __shared__ float w3s[NFC2*2];
    __shared__ float b1s[NFC1], b2s[NFC2], b3s[2];
    const int tid = threadIdx.x;
    for (int i = tid; i < RNNCH*NFC1; i += 256) w1s[i/NFC1][i%NFC1] = W1[i];
    for (int i = tid; i < NFC1*NFC2; i += 256) w2s[i] = W2[i];
    for (int i = tid; i < NFC2*2;   i += 256) w3s[i] = W3[i];
    if (tid < NFC1) b1s[tid] = B1[tid];
    if (tid < NFC2) b2s[tid] = B2[tid];
    if (tid < 2)    b3s[tid] = B3[tid];
    __syncthreads();

    const size_t row = (size_t)blockIdx.x*256 + tid;
    const float* __restrict__ in = rnn + row*RNNCH;

    float h[NFC1];
    #pragma unroll
    for (int j = 0; j < NFC1; ++j) h[j] = b1s[j];
    #pragma unroll 4
    for (int c = 0; c < RNNCH; ++c) {
        float v = in[c];
        #pragma unroll
        for (int j = 0; j < NFC1; ++j) h[j] += v * w1s[c][j];
    }
    #pragma unroll
    for (int j = 0; j < NFC1; ++j) h[j] = fmaxf(h[j], 0.0f);

    float h2[NFC2];
    #pragma unroll
    for (int j = 0; j < NFC2; ++j) h2[j] = b2s[j];
    #pragma unroll        // full unroll: h[c] must be a static register index
    for (int c = 0; c < NFC1; ++c) {
        float v = h[c];
        #pragma unroll
        for (int j = 0; j < NFC2; ++j) h2[j] += v * w2s[c*NFC2 + j];
    }
    #pragma unroll
    for (int j = 0; j < NFC2; ++j) h2[j] = fmaxf(h2[j], 0.0f);

    float o0 = b3s[0], o1 = b3s[1];
    #pragma unroll        // full unroll: h2[c] static index
    for (int c = 0; c < NFC2; ++c) {
        o0 += h2[c] * w3s[c*2];
        o1 += h2[c] * w3s[c*2+1];
    }
    ((float2*)out)[row] = make_float2(o0, o1);
}

extern "C" void kernel_launch(void* const* d_in, const int* in_sizes, int n_in,
                              void* d_out, int out_size, void* d_ws, size_t ws_size,
                              hipStream_t stream) {
    (void)in_sizes; (void)n_in; (void)out_size; (void)ws_size;
    const float* x     = (const float*)d_in[0];
    const float* w_fw1 = (const float*)d_in[1];
    const float* b_fw1 = (const float*)d_in[2];
    const float* w_fw2 = (const float*)d_in[3];
    const float* b_fw2 = (const float*)d_in[4];
    const float* w_bw1 = (const float*)d_in[5];
    const float* b_bw1 = (const float*)d_in[6];
    const float* w_bw2 = (const float*)d_in[7];
    const float* b_bw2 = (const float*)d_in[8];
    const float* w_fc1 = (const float*)d_in[9];
    const float* b_fc1 = (const float*)d_in[10];
    const float* w_fc2 = (const float*)d_in[11];
    const float* b_fc2 = (const float*)d_in[12];
    const float* w_fc3 = (const float*)d_in[13];
    const float* b_fc3 = (const float*)d_in[14];
    float* out = (float*)d_out;

    float* rnn = (float*)d_ws;                 // B*T*60 floats = ~295 MB

    dim3 gl(BB/RPB, 2), bl(TX, TY);            // 256 blocks = 1/CU
    lstm2_kernel<<<gl, bl, 0, stream>>>(x, w_fw1, b_fw1, w_fw2, b_fw2,
                                        w_bw1, b_bw1, w_bw2, b_bw2, rnn);

    const int total = BB * TT;                  // 1,228,800 (exact multiple of 256)
    fc_kernel<<<total/256, 256, 0, stream>>>(rnn, w_fc1, b_fc1, w_fc2, b_fc2,
                                             w_fc3, b_fc3, out);
}

// Round 3
// 1456.447 us; speedup vs baseline: 2.6971x; 2.0710x over previous
//
#include <hip/hip_runtime.h>

#define TT 300
#define FF 39
#define H1C 35
#define H2C 30
#define BB 4096
#define RPB 32          // batch rows per block (= M)
#define NTH 512         // 8 waves
#define AP 104          // padded A-row stride in bf16 elems (96 + 8: balanced banks)
#define ZTP 36          // zT row stride in f32 (16B-aligned, 2-way max)
#define NFC1 50
#define NFC2 40
#define RNNCH 60

typedef __attribute__((ext_vector_type(8))) short s8v;   // 8 bf16 (4 VGPR) MFMA A/B frag
typedef __attribute__((ext_vector_type(4))) float f4v;   // MFMA C/D frag

__device__ __forceinline__ float sigf(float v){ return 1.0f/(1.0f+__expf(-v)); }
__device__ __forceinline__ float tanh_(float v){ return 1.0f - 2.0f/(__expf(2.0f*v)+1.0f); }

__device__ __forceinline__ unsigned short bf16rne(float f){
  unsigned u = __float_as_uint(f);
  return (unsigned short)((u + 0x7fffu + ((u>>16)&1u)) >> 16);
}
// split f into bf16 hi + bf16 lo (f ~= hi + lo to ~2^-17 rel)
__device__ __forceinline__ void split2(float f, unsigned short& hi, unsigned short& lo){
  hi = bf16rne(f);
  float fh = __uint_as_float(((unsigned)hi)<<16);
  lo = bf16rne(f - fh);
}

// Bidirectional stacked-LSTM via split-bf16 MFMA. blockIdx.y = direction.
// 256 blocks = 1/CU, 8 waves each.
// K padded to 96: layer1 in = [x(39)+pad9 | h1(35)+pad13]; layer2 in = [h1(35)+pad13 | h2(30)+pad18]
// -> every (lane>>4)*8 A-frag slice lies in one region.
__global__ __launch_bounds__(NTH, 2)
void lstm2_mfma(const float* __restrict__ x,
                const float* __restrict__ Wf1, const float* __restrict__ Bf1,
                const float* __restrict__ Wf2, const float* __restrict__ Bf2,
                const float* __restrict__ Wb1, const float* __restrict__ Bb1,
                const float* __restrict__ Wb2, const float* __restrict__ Bb2,
                float* __restrict__ rnn)
{
  __shared__ __align__(16) unsigned short A1h[RPB][AP], A1l[RPB][AP];  // layer-1 input, hi/lo
  __shared__ __align__(16) unsigned short A2h[RPB][AP], A2l[RPB][AP];  // layer-2 input, hi/lo
  __shared__ __align__(16) float zT[144][ZTP];                         // z transposed: [col][row]
  // LDS total = 4*32*104*2 + 144*36*4 = 26,624 + 20,736 = 47,360 B

  const int dir = blockIdx.y;
  const int b0  = blockIdx.x * RPB;
  const float* W1 = dir ? Wb1 : Wf1; const float* B1 = dir ? Bb1 : Bf1;
  const float* W2 = dir ? Wb2 : Wf2; const float* B2 = dir ? Bb2 : Bf2;

  const int tid  = threadIdx.x;
  const int lane = tid & 63, w = tid >> 6;      // 8 waves
  const int fr   = lane & 15, kgq = lane >> 4;  // frag row/col, k-group

  // ---- B-fragment gather (once; step-invariant, lives in registers) ----
  // b-frag elem j = W[k = kc*32 + kgq*8 + j][col = nt*16 + fr]  (gemm_bt form)
  s8v B1hf[2][3], B1lf[2][3], B2hf[3], B2lf[3];
  for (int slot = 0; slot < 2; ++slot) {
    const int nt = (slot==0) ? w : 8;           // wave0 also owns N-tile 8 (cols 128..143)
    const bool act = (slot==0) || (w==0);
    for (int kc = 0; kc < 3; ++kc) {
      s8v vh, vl;
      #pragma unroll
      for (int j = 0; j < 8; ++j) {
        float wv = 0.f;
        if (act) {
          int k = kc*32 + kgq*8 + j;
          int col = nt*16 + fr;
          int ks = (k < 39) ? k : (k >= 48 && k < 83) ? 39 + (k-48) : -1;  // x rows / h1 rows
          if (ks >= 0 && col < 140) wv = W1[ks*140 + col];
        }
        unsigned short h_, l_; split2(wv, h_, l_);
        vh[j] = (short)h_; vl[j] = (short)l_;
      }
      B1hf[slot][kc] = vh; B1lf[slot][kc] = vl;
    }
  }
  for (int kc = 0; kc < 3; ++kc) {
    s8v vh, vl;
    #pragma unroll
    for (int j = 0; j < 8; ++j) {
      float wv = 0.f;
      int k = kc*32 + kgq*8 + j;
      int col = w*16 + fr;
      int ks = (k < 35) ? k : (k >= 48 && k < 78) ? 35 + (k-48) : -1;      // h1 rows / h2 rows
      if (ks >= 0 && col < 120) wv = W2[ks*120 + col];
      unsigned short h_, l_; split2(wv, h_, l_);
      vh[j] = (short)h_; vl[j] = (short)l_;
    }
    B2hf[kc] = vh; B2lf[kc] = vl;
  }

  // ---- epilogue unit assignment (step-invariant). u -> (r = u%32, k = u/32): conflict-free zT reads ----
  int k1v[3], r1v[3]; float bias1[3][4]; bool act1[3];
  #pragma unroll
  for (int s = 0; s < 3; ++s) {
    int u = tid + s*NTH; act1[s] = (u < H1C*RPB);
    int uu = act1[s] ? u : 0;
    r1v[s] = uu & 31; k1v[s] = uu >> 5;
    #pragma unroll
    for (int g = 0; g < 4; ++g) bias1[s][g] = B1[g*H1C + k1v[s]];
  }
  int k2v[2], r2v[2]; float bias2[2][4]; bool act2[2];
  #pragma unroll
  for (int s = 0; s < 2; ++s) {
    int u = tid + s*NTH; act2[s] = (u < H2C*RPB);
    int uu = act2[s] ? u : 0;
    r2v[s] = uu & 31; k2v[s] = uu >> 5;
    #pragma unroll
    for (int g = 0; g < 4; ++g) bias2[s][g] = B2[g*H2C + k2v[s]];
  }

  // ---- zero A-staging (pads + h regions), then stage x(t=first) ----
  for (int i = tid; i < RPB*AP; i += NTH) {
    ((unsigned short*)A1h)[i] = 0; ((unsigned short*)A1l)[i] = 0;
    ((unsigned short*)A2h)[i] = 0; ((unsigned short*)A2l)[i] = 0;
  }
  __syncthreads();
  const int t0in = dir ? (TT-1) : 0;
  #pragma unroll
  for (int s = 0; s < 3; ++s) {
    int e = tid + s*NTH;
    if (e < RPB*FF) {
      int r = e/FF, c = e%FF;
      float f = x[((size_t)(b0+r)*TT + t0in)*FF + c];
      unsigned short h_, l_; split2(f, h_, l_);
      A1h[r][c] = h_; A1l[r][c] = l_;
    }
  }
  __syncthreads();

  float c1s[3] = {0.f,0.f,0.f}, c2s[2] = {0.f,0.f};

  #pragma unroll 1
  for (int t = 0; t < TT; ++t) {
    // prefetch x(t+1) -> regs (latency hidden under P1+P2)
    float xp[3];
    const bool pf = (t+1 < TT);
    const int tn = dir ? (TT-2-t) : (t+1);
    #pragma unroll
    for (int s = 0; s < 3; ++s) {
      xp[s] = 0.f;
      int e = tid + s*NTH;
      if (pf && e < RPB*FF)
        xp[s] = x[((size_t)(b0 + e/FF)*TT + tn)*FF + (e%FF)];
    }

    // ---- P1: layer-1 A-frags + MFMA + zT write ----
    s8v a1h[2][3], a1l[2][3];
    #pragma unroll
    for (int Mt = 0; Mt < 2; ++Mt) {
      int m = Mt*16 + fr;
      #pragma unroll
      for (int kc = 0; kc < 3; ++kc) {
        int kb = kc*32 + kgq*8;
        a1h[Mt][kc] = *(const s8v*)&A1h[m][kb];
        a1l[Mt][kc] = *(const s8v*)&A1l[m][kb];
      }
    }
    for (int slot = 0; slot < 2; ++slot) {
      if (slot == 1 && w != 0) continue;
      const int nt = (slot==0) ? w : 8;
      #pragma unroll
      for (int Mt = 0; Mt < 2; ++Mt) {
        f4v acc = {0.f,0.f,0.f,0.f};
        #pragma unroll
        for (int kc = 0; kc < 3; ++kc) {
          acc = __builtin_amdgcn_mfma_f32_16x16x32_bf16(a1h[Mt][kc], B1hf[slot][kc], acc, 0,0,0);
          acc = __builtin_amdgcn_mfma_f32_16x16x32_bf16(a1h[Mt][kc], B1lf[slot][kc], acc, 0,0,0);
          acc = __builtin_amdgcn_mfma_f32_16x16x32_bf16(a1l[Mt][kc], B1hf[slot][kc], acc, 0,0,0);
        }
        *(f4v*)&zT[nt*16 + fr][Mt*16 + kgq*4] = acc;  // C: col=lane&15, rows (lane>>4)*4+j
      }
    }
    __syncthreads();  // B1: zT1 ready; A1 frag reads done

    // ---- P2: layer-1 epilogue (gates -> h1), stage h1 + x(t+1) ----
    #pragma unroll
    for (int s = 0; s < 3; ++s) {
      if (act1[s]) {
        int k = k1v[s], r = r1v[s];
        float zi = zT[k][r]       + bias1[s][0];
        float zj = zT[35+k][r]    + bias1[s][1];
        float zf = zT[70+k][r]    + bias1[s][2];
        float zo = zT[105+k][r]   + bias1[s][3];
        c1s[s] = sigf(zf + 1.f)*c1s[s] + sigf(zi)*tanh_(zj);
        float h = sigf(zo)*tanh_(c1s[s]);
        unsigned short h_, l_; split2(h, h_, l_);
        A2h[r][k] = h_;      A2l[r][k] = l_;       // layer-2 input (this step)
        A1h[r][48+k] = h_;   A1l[r][48+k] = l_;    // layer-1 input (next step)
      }
    }
    if (pf) {
      #pragma unroll
      for (int s = 0; s < 3; ++s) {
        int e = tid + s*NTH;
        if (e < RPB*FF) {
          int r = e/FF, c = e%FF;
          unsigned short h_, l_; split2(xp[s], h_, l_);
          A1h[r][c] = h_; A1l[r][c] = l_;
        }
      }
    }
    __syncthreads();  // B2: A2 h1-region + A1 next-step ready; zT1 reads done

    // ---- P3: layer-2 A-frags + MFMA + zT write ----
    s8v a2h[2][3], a2l[2][3];
    #pragma unroll
    for (int Mt = 0; Mt < 2; ++Mt) {
      int m = Mt*16 + fr;
      #pragma unroll
      for (int kc = 0; kc < 3; ++kc) {
        int kb = kc*32 + kgq*8;
        a2h[Mt][kc] = *(const s8v*)&A2h[m][kb];
        a2l[Mt][kc] = *(const s8v*)&A2l[m][kb];
      }
    }
    #pragma unroll
    for (int Mt = 0; Mt < 2; ++Mt) {
      f4v acc = {0.f,0.f,0.f,0.f};
      #pragma unroll
      for (int kc = 0; kc < 3; ++kc) {
        acc = __builtin_amdgcn_mfma_f32_16x16x32_bf16(a2h[Mt][kc], B2hf[kc], acc, 0,0,0);
        acc = __builtin_amdgcn_mfma_f32_16x16x32_bf16(a2h[Mt][kc], B2lf[kc], acc, 0,0,0);
        acc = __builtin_amdgcn_mfma_f32_16x16x32_bf16(a2l[Mt][kc], B2hf[kc], acc, 0,0,0);
      }
      *(f4v*)&zT[w*16 + fr][Mt*16 + kgq*4] = acc;
    }
    __syncthreads();  // B3: zT2 ready; A2 reads done

    // ---- P4: layer-2 epilogue (gates -> h2), stage h2 (next step) + write rnn ----
    const int tout = dir ? (TT-1-t) : t;
    #pragma unroll
    for (int s = 0; s < 2; ++s) {
      if (act2[s]) {
        int k = k2v[s], r = r2v[s];
        float zi = zT[k][r]      + bias2[s][0];
        float zj = zT[30+k][r]   + bias2[s][1];
        float zf = zT[60+k][r]   + bias2[s][2];
        float zo = zT[90+k][r]   + bias2[s][3];
        c2s[s] = sigf(zf + 1.f)*c2s[s] + sigf(zi)*tanh_(zj);
        float h = sigf(zo)*tanh_(c2s[s]);
        unsigned short h_, l_; split2(h, h_, l_);
        A2h[r][48+k] = h_; A2l[r][48+k] = l_;      // layer-2 h2 input (next step)
        rnn[(((size_t)(b0+r)*TT) + tout)*RNNCH + dir*H2C + k] = h;
      }
    }
    __syncthreads();  // B4: A2 h2-region ready for next P3; zT2 reads done before next P1 write
  }
}

// Pointwise 3-layer MLP on the concatenated rnn features. (unchanged, ~37 us)
__global__ __launch_bounds__(256)
void fc_kernel(const float* __restrict__ rnn,
               const float* __restrict__ W1, const float* __restrict__ B1,
               const float* __restrict__ W2, const float* __restrict__ B2,
               const float* __restrict__ W3, const float* __restrict__ B3,
               float* __restrict__ out)
{
    __shared__ float w1s[RNNCH][52];
    __shared__ float w2s[NFC1*NFC2];
    __shared__ float w3s[NFC2*2];
    __shared__ float b1s[NFC1], b2s[NFC2], b3s[2];
    const int tid = threadIdx.x;
    for (int i = tid; i < RNNCH*NFC1; i += 256) w1s[i/NFC1][i%NFC1] = W1[i];
    for (int i = tid; i < NFC1*NFC2; i += 256) w2s[i] = W2[i];
    for (int i = tid; i < NFC2*2;   i += 256) w3s[i] = W3[i];
    if (tid < NFC1) b1s[tid] = B1[tid];
    if (tid < NFC2) b2s[tid] = B2[tid];
    if (tid < 2)    b3s[tid] = B3[tid];
    __syncthreads();

    const size_t row = (size_t)blockIdx.x*256 + tid;
    const float* __restrict__ in = rnn + row*RNNCH;

    float h[NFC1];
    #pragma unroll
    for (int j = 0; j < NFC1; ++j) h[j] = b1s[j];
    #pragma unroll 4
    for (int c = 0; c < RNNCH; ++c) {
        float v = in[c];
        #pragma unroll
        for (int j = 0; j < NFC1; ++j) h[j] += v * w1s[c][j];
    }
    #pragma unroll
    for (int j = 0; j < NFC1; ++j) h[j] = fmaxf(h[j], 0.0f);

    float h2[NFC2];
    #pragma unroll
    for (int j = 0; j < NFC2; ++j) h2[j] = b2s[j];
    #pragma unroll
    for (int c = 0; c < NFC1; ++c) {
        float v = h[c];
        #pragma unroll
        for (int j = 0; j < NFC2; ++j) h2[j] += v * w2s[c*NFC2 + j];
    }
    #pragma unroll
    for (int j = 0; j < NFC2; ++j) h2[j] = fmaxf(h2[j], 0.0f);

    float o0 = b3s[0], o1 = b3s[1];
    #pragma unroll
    for (int c = 0; c < NFC2; ++c) {
        o0 += h2[c] * w3s[c*2];
        o1 += h2[c] * w3s[c*2+1];
    }
    ((float2*)out)[row] = make_float2(o0, o1);
}

extern "C" void kernel_launch(void* const* d_in, const int* in_sizes, int n_in,
                              void* d_out, int out_size, void* d_ws, size_t ws_size,
                              hipStream_t stream) {
    (void)in_sizes; (void)n_in; (void)out_size; (void)ws_size;
    const float* x     = (const float*)d_in[0];
    const float* w_fw1 = (const float*)d_in[1];
    const float* b_fw1 = (const float*)d_in[2];
    const float* w_fw2 = (const float*)d_in[3];
    const float* b_fw2 = (const float*)d_in[4];
    const float* w_bw1 = (const float*)d_in[5];
    const float* b_bw1 = (const float*)d_in[6];
    const float* w_bw2 = (const float*)d_in[7];
    const float* b_bw2 = (const float*)d_in[8];
    const float* w_fc1 = (const float*)d_in[9];
    const float* b_fc1 = (const float*)d_in[10];
    const float* w_fc2 = (const float*)d_in[11];
    const float* b_fc2 = (const float*)d_in[12];
    const float* w_fc3 = (const float*)d_in[13];
    const float* b_fc3 = (const float*)d_in[14];
    float* out = (float*)d_out;

    float* rnn = (float*)d_ws;                 // B*T*60 f32 = ~295 MB

    dim3 gl(BB/RPB, 2);                        // 128 x 2 = 256 blocks = 1/CU
    lstm2_mfma<<<gl, NTH, 0, stream>>>(x, w_fw1, b_fw1, w_fw2, b_fw2,
                                       w_bw1, b_bw1, w_bw2, b_bw2, rnn);

    const int total = BB * TT;                  // 1,228,800
    fc_kernel<<<total/256, 256, 0, stream>>>(rnn, w_fc1, b_fc1, w_fc2, b_fc2,
                                             w_fc3, b_fc3, out);
}

// Round 4
// 1356.852 us; speedup vs baseline: 2.8951x; 1.0734x over previous
//
#include <hip/hip_runtime.h>

#define TT 300
#define FF 39
#define H1C 35
#define H2C 30
#define BB 4096
#define RPB 32          // batch rows per block (= M)
#define NTH 512         // 8 waves = 2 M-waves x 4 N-waves
#define AP 104          // A-row stride in bf16 elems (K=96 + 8 pad)
#define NFC1 50
#define NFC2 40
#define RNNCH 60

typedef __attribute__((ext_vector_type(8))) short s8v;   // 8 bf16 MFMA A/B frag
typedef __attribute__((ext_vector_type(4))) float f4v;   // MFMA C/D frag

__device__ __forceinline__ float sigf(float v){ return 1.0f/(1.0f+__expf(-v)); }
__device__ __forceinline__ float tanh_(float v){ return 1.0f - 2.0f/(__expf(2.0f*v)+1.0f); }

__device__ __forceinline__ unsigned short bf16rne(float f){
  unsigned u = __float_as_uint(f);
  return (unsigned short)((u + 0x7fffu + ((u>>16)&1u)) >> 16);
}
__device__ __forceinline__ void split2(float f, unsigned short& hi, unsigned short& lo){
  hi = bf16rne(f);
  float fh = __uint_as_float(((unsigned)hi)<<16);
  lo = bf16rne(f - fh);
}

template<int CTRL>
__device__ __forceinline__ float dppq(float v){
  return __int_as_float(__builtin_amdgcn_update_dpp(0, __float_as_int(v), CTRL, 0xF, 0xF, true));
}
// 4x4 transpose across quad lanes (q = lane&3) x regs. After: a_r = old (quadlane=r, reg=q).
__device__ __forceinline__ void tr4(float&a0,float&a1,float&a2,float&a3,int q){
  float t0=dppq<0xB1>(a1), t1=dppq<0xB1>(a0), t2=dppq<0xB1>(a3), t3=dppq<0xB1>(a2); // xor 1
  bool g0 = (q & 1);
  a0 = g0 ? t0 : a0;
  a1 = g0 ? a1 : t1;
  a2 = g0 ? t2 : a2;
  a3 = g0 ? a3 : t3;
  float s0=dppq<0x4E>(a2), s1=dppq<0x4E>(a3), s2=dppq<0x4E>(a0), s3=dppq<0x4E>(a1); // xor 2
  bool g1 = (q & 2);
  a0 = g1 ? s0 : a0;
  a1 = g1 ? s1 : a1;
  a2 = g1 ? a2 : s2;
  a3 = g1 ? a3 : s3;
}

// Bidirectional stacked-LSTM, split-bf16 MFMA, gate-interleaved B, in-register epilogue.
// 256 blocks = 1/CU. One barrier per time step (double-buffered A staging).
// K layout (both layers): input0 at k 0..len0-1, input1 at k 48..48+len1-1, rest zero-pad.
__global__ __launch_bounds__(NTH, 2)
void lstm2_mfma(const float* __restrict__ x,
                const float* __restrict__ Wf1, const float* __restrict__ Bf1,
                const float* __restrict__ Wf2, const float* __restrict__ Bf2,
                const float* __restrict__ Wb1, const float* __restrict__ Bb1,
                const float* __restrict__ Wb2, const float* __restrict__ Bb2,
                float* __restrict__ rnn)
{
  __shared__ __align__(16) unsigned short A1h[2][RPB*AP], A1l[2][RPB*AP];
  __shared__ __align__(16) unsigned short A2h[2][RPB*AP], A2l[2][RPB*AP];
  // LDS = 8 * 32*104 * 2B = 53,248 B

  const int dir = blockIdx.y;
  const int b0  = blockIdx.x * RPB;
  const float* W1  = dir ? Wb1 : Wf1; const float* B1v = dir ? Bb1 : Bf1;
  const float* W2  = dir ? Wb2 : Wf2; const float* B2v = dir ? Bb2 : Bf2;

  const int tid  = threadIdx.x;
  const int lane = tid & 63, w = tid >> 6;
  const int wm = w & 1, wn = w >> 1;            // 2 M-waves x 4 N-waves
  const int fr = lane & 15, kgq = lane >> 4;
  const int qp = lane & 3, u4 = (lane >> 2) & 3;

  // ---- B-fragment gather (gate-interleaved: col = 4*unit + gate) ----
  // L1: 9 N-tiles (144 cols) -> wn<3: tiles {2wn,2wn+1}; wn==3: {6,7,8}
  // L2: 8 N-tiles (128 cols) -> tiles {2wn, 2wn+1}
  s8v B1h_[3][3], B1l_[3][3], B2h_[2][3], B2l_[2][3];
  bool act1s[3];
  #pragma unroll
  for (int s = 0; s < 3; ++s) {
    act1s[s] = (s < 2) || (wn == 3);
    const int T = 2*wn + s;
    #pragma unroll
    for (int kc = 0; kc < 3; ++kc) {
      s8v vh, vl;
      #pragma unroll
      for (int j = 0; j < 8; ++j) {
        float wv = 0.f;
        if (act1s[s]) {
          int k = kc*32 + kgq*8 + j;
          int col = 16*T + fr;
          int u = col >> 2, g = col & 3;
          int ks = (k < FF) ? k : (k >= 48 && k < 48+H1C) ? FF + (k-48) : -1;
          if (ks >= 0 && u < H1C) wv = W1[ks*(4*H1C) + g*H1C + u];
        }
        unsigned short h_, l_; split2(wv, h_, l_);
        vh[j] = (short)h_; vl[j] = (short)l_;
      }
      B1h_[s][kc] = vh; B1l_[s][kc] = vl;
    }
  }
  #pragma unroll
  for (int s = 0; s < 2; ++s) {
    const int T = 2*wn + s;
    #pragma unroll
    for (int kc = 0; kc < 3; ++kc) {
      s8v vh, vl;
      #pragma unroll
      for (int j = 0; j < 8; ++j) {
        float wv = 0.f;
        int k = kc*32 + kgq*8 + j;
        int col = 16*T + fr;
        int u = col >> 2, g = col & 3;
        int ks = (k < H1C) ? k : (k >= 48 && k < 48+H2C) ? H1C + (k-48) : -1;
        if (ks >= 0 && u < H2C) wv = W2[ks*(4*H2C) + g*H2C + u];
        unsigned short h_, l_; split2(wv, h_, l_);
        vh[j] = (short)h_; vl[j] = (short)l_;
      }
      B2h_[s][kc] = vh; B2l_[s][kc] = vl;
    }
  }

  // ---- biases (per-lane unit, gathered once) ----
  float4 bias1[3], bias2[2];
  #pragma unroll
  for (int s = 0; s < 3; ++s) {
    int u = 4*(2*wn + s) + u4; int uc = u < H1C ? u : H1C-1;
    bias1[s] = make_float4(B1v[uc], B1v[H1C+uc], B1v[2*H1C+uc], B1v[3*H1C+uc]);
  }
  #pragma unroll
  for (int s = 0; s < 2; ++s) {
    int u = 4*(2*wn + s) + u4; int uc = u < H2C ? u : H2C-1;
    bias2[s] = make_float4(B2v[uc], B2v[H2C+uc], B2v[2*H2C+uc], B2v[3*H2C+uc]);
  }

  // ---- zero all staging, then stage x(t=first) into parity 0 ----
  for (int i = tid; i < 2*RPB*AP; i += NTH) {
    ((unsigned short*)A1h)[i] = 0; ((unsigned short*)A1l)[i] = 0;
    ((unsigned short*)A2h)[i] = 0; ((unsigned short*)A2l)[i] = 0;
  }
  __syncthreads();
  const int t0in = dir ? (TT-1) : 0;
  #pragma unroll
  for (int s = 0; s < 3; ++s) {
    int e = tid + s*NTH;
    if (e < RPB*FF) {
      int r = e/FF, c = e%FF;
      float f = x[((size_t)(b0+r)*TT + t0in)*FF + c];
      unsigned short h_, l_; split2(f, h_, l_);
      A1h[0][r*AP+c] = h_; A1l[0][r*AP+c] = l_;
    }
  }
  __syncthreads();

  float c1[3] = {0.f,0.f,0.f}, c2[2] = {0.f,0.f};
  const int mrow = wm*16 + fr;
  const int rr   = wm*16 + kgq*4 + qp;          // epilogue row of this lane

  #pragma unroll 1
  for (int t = 0; t < TT; ++t) {
    const int p = t & 1, pn = p ^ 1;
    const bool pf = (t+1 < TT);
    const int tn = dir ? (TT-2-t) : (t+1);

    // prefetch x(t+1) -> regs
    float xp[3];
    #pragma unroll
    for (int s = 0; s < 3; ++s) {
      xp[s] = 0.f;
      int e = tid + s*NTH;
      if (pf && e < RPB*FF)
        xp[s] = x[((size_t)(b0 + e/FF)*TT + tn)*FF + (e%FF)];
    }

    // ---- P1: layer-1 frags, MFMA, in-register epilogue ----
    s8v a1hf[3], a1lf[3];
    #pragma unroll
    for (int kc = 0; kc < 3; ++kc) {
      int off = mrow*AP + kc*32 + kgq*8;
      a1hf[kc] = *(const s8v*)&A1h[p][off];
      a1lf[kc] = *(const s8v*)&A1l[p][off];
    }
    #pragma unroll
    for (int s = 0; s < 3; ++s) {
      if (act1s[s]) {
        f4v acc = {0.f,0.f,0.f,0.f};
        #pragma unroll
        for (int kc = 0; kc < 3; ++kc) {
          acc = __builtin_amdgcn_mfma_f32_16x16x32_bf16(a1hf[kc], B1h_[s][kc], acc, 0,0,0);
          acc = __builtin_amdgcn_mfma_f32_16x16x32_bf16(a1hf[kc], B1l_[s][kc], acc, 0,0,0);
          acc = __builtin_amdgcn_mfma_f32_16x16x32_bf16(a1lf[kc], B1h_[s][kc], acc, 0,0,0);
        }
        float z0 = acc[0], z1 = acc[1], z2 = acc[2], z3 = acc[3];
        tr4(z0, z1, z2, z3, qp);                 // lane now holds gates i,j,f,o of (rr, unit)
        float zi = z0 + bias1[s].x, zj = z1 + bias1[s].y;
        float zf = z2 + bias1[s].z, zo = z3 + bias1[s].w;
        float cn = sigf(zf + 1.f)*c1[s] + sigf(zi)*tanh_(zj);
        c1[s] = cn;
        float h = sigf(zo)*tanh_(cn);
        unsigned short h_, l_; split2(h, h_, l_);
        int u = 4*(2*wn + s) + u4;
        A2h[p][rr*AP + u] = h_;       A2l[p][rr*AP + u] = l_;        // layer-2 input (this step)
        A1h[pn][rr*AP + 48 + u] = h_; A1l[pn][rr*AP + 48 + u] = l_;  // layer-1 input (next step)
      }
    }
    // stage x(t+1) into next-parity buffer
    if (pf) {
      #pragma unroll
      for (int s = 0; s < 3; ++s) {
        int e = tid + s*NTH;
        if (e < RPB*FF) {
          int r = e/FF, c = e%FF;
          unsigned short h_, l_; split2(xp[s], h_, l_);
          A1h[pn][r*AP+c] = h_; A1l[pn][r*AP+c] = l_;
        }
      }
    }
    __syncthreads();   // the ONLY barrier per step: h1 (A2[p]) ready for P2

    // ---- P2: layer-2 frags, MFMA, epilogue, rnn store ----
    s8v a2hf[3], a2lf[3];
    #pragma unroll
    for (int kc = 0; kc < 3; ++kc) {
      int off = mrow*AP + kc*32 + kgq*8;
      a2hf[kc] = *(const s8v*)&A2h[p][off];
      a2lf[kc] = *(const s8v*)&A2l[p][off];
    }
    const int tout = dir ? (TT-1-t) : t;
    #pragma unroll
    for (int s = 0; s < 2; ++s) {
      f4v acc = {0.f,0.f,0.f,0.f};
      #pragma unroll
      for (int kc = 0; kc < 3; ++kc) {
        acc = __builtin_amdgcn_mfma_f32_16x16x32_bf16(a2hf[kc], B2h_[s][kc], acc, 0,0,0);
        acc = __builtin_amdgcn_mfma_f32_16x16x32_bf16(a2hf[kc], B2l_[s][kc], acc, 0,0,0);
        acc = __builtin_amdgcn_mfma_f32_16x16x32_bf16(a2lf[kc], B2h_[s][kc], acc, 0,0,0);
      }
      float z0 = acc[0], z1 = acc[1], z2 = acc[2], z3 = acc[3];
      tr4(z0, z1, z2, z3, qp);
      float zi = z0 + bias2[s].x, zj = z1 + bias2[s].y;
      float zf = z2 + bias2[s].z, zo = z3 + bias2[s].w;
      float cn = sigf(zf + 1.f)*c2[s] + sigf(zi)*tanh_(zj);
      c2[s] = cn;
      float h = sigf(zo)*tanh_(cn);
      unsigned short h_, l_; split2(h, h_, l_);
      int u = 4*(2*wn + s) + u4;
      A2h[pn][rr*AP + 48 + u] = h_; A2l[pn][rr*AP + 48 + u] = l_;    // h2 for next step
      if (u < H2C)
        rnn[(((size_t)(b0+rr)*TT) + tout)*RNNCH + dir*H2C + u] = h;
    }
    // no trailing barrier needed: next P1 touches only A1[pn]/A2[pn]-h1, all
    // consumers of this phase's writes are separated by the next step's barrier.
  }
}

// Pointwise 3-layer MLP. Weights via wave-uniform global reads (scalar pipe),
// h1 bounced through a private LDS row to allow a runtime c-loop.
__global__ __launch_bounds__(256)
void fc_kernel(const float* __restrict__ rnn,
               const float* __restrict__ W1, const float* __restrict__ B1,
               const float* __restrict__ W2, const float* __restrict__ B2,
               const float* __restrict__ W3, const float* __restrict__ B3,
               float* __restrict__ out)
{
    __shared__ float hbuf[256][53];     // stride 53: odd -> 2-way max on banks
    const int tid = threadIdx.x;
    const size_t row = (size_t)blockIdx.x*256 + tid;
    const float4* __restrict__ inp = (const float4*)(rnn + row*RNNCH);

    float h[NFC1];
    #pragma unroll
    for (int j = 0; j < NFC1; ++j) h[j] = B1[j];
    #pragma unroll 1
    for (int s = 0; s < 15; ++s) {
        float4 v = inp[s];
        const float* wp = W1 + (4*s)*NFC1;       // uniform -> s_load
        #pragma unroll
        for (int j = 0; j < NFC1; ++j)
            h[j] += v.x*wp[j] + v.y*wp[NFC1+j] + v.z*wp[2*NFC1+j] + v.w*wp[3*NFC1+j];
    }
    #pragma unroll
    for (int j = 0; j < NFC1; ++j) hbuf[tid][j] = fmaxf(h[j], 0.0f);

    float h2[NFC2];
    #pragma unroll
    for (int j = 0; j < NFC2; ++j) h2[j] = B2[j];
    #pragma unroll 1
    for (int c = 0; c < NFC1; ++c) {
        float v = hbuf[tid][c];                  // own row: no barrier needed
        const float* wp = W2 + c*NFC2;           // uniform -> s_load
        #pragma unroll
        for (int j = 0; j < NFC2; ++j) h2[j] += v*wp[j];
    }

    float o0 = B3[0], o1 = B3[1];
    #pragma unroll
    for (int c = 0; c < NFC2; ++c) {
        float v = fmaxf(h2[c], 0.0f);
        o0 += v*W3[2*c]; o1 += v*W3[2*c+1];
    }
    ((float2*)out)[row] = make_float2(o0, o1);
}

extern "C" void kernel_launch(void* const* d_in, const int* in_sizes, int n_in,
                              void* d_out, int out_size, void* d_ws, size_t ws_size,
                              hipStream_t stream) {
    (void)in_sizes; (void)n_in; (void)out_size; (void)ws_size;
    const float* x     = (const float*)d_in[0];
    const float* w_fw1 = (const float*)d_in[1];
    const float* b_fw1 = (const float*)d_in[2];
    const float* w_fw2 = (const float*)d_in[3];
    const float* b_fw2 = (const float*)d_in[4];
    const float* w_bw1 = (const float*)d_in[5];
    const float* b_bw1 = (const float*)d_in[6];
    const float* w_bw2 = (const float*)d_in[7];
    const float* b_bw2 = (const float*)d_in[8];
    const float* w_fc1 = (const float*)d_in[9];
    const float* b_fc1 = (const float*)d_in[10];
    const float* w_fc2 = (const float*)d_in[11];
    const float* b_fc2 = (const float*)d_in[12];
    const float* w_fc3 = (const float*)d_in[13];
    const float* b_fc3 = (const float*)d_in[14];
    float* out = (float*)d_out;

    float* rnn = (float*)d_ws;                 // B*T*60 f32 = ~295 MB

    dim3 gl(BB/RPB, 2);                        // 128 x 2 = 256 blocks = 1/CU
    lstm2_mfma<<<gl, NTH, 0, stream>>>(x, w_fw1, b_fw1, w_fw2, b_fw2,
                                       w_bw1, b_bw1, w_bw2, b_bw2, rnn);

    const int total = BB * TT;                  // 1,228,800
    fc_kernel<<<total/256, 256, 0, stream>>>(rnn, w_fc1, b_fc1, w_fc2, b_fc2,
                                             w_fc3, b_fc3, out);
}